// Round 12
// baseline (25.312 us; speedup 1.0000x reference)
//
#include <hip/hip_runtime.h>

// Rydberg Hamiltonian apply, two-pass butterfly:
//   P1: out[k]  = diag(k)*s[k] + sum_{b=13..21} c_b s[k^2^b]   (hi bits via LDS)
//   P2: out[k] += sum_{b=0..12} c_b s[k^2^b]                    (lo bits via LDS/regs)
// Element bit b <-> qubit (21-b); c_b = 0.5*rabi[21-b]. DIM=2^22.
// VMEM per output f4: 5 (P1 1R+1W, P2 2R+1W) vs 11 in the single-pass kernel.
// All inter-pass traffic is L3-resident (48MB working set << 256MB L3);
// P1 stores PLAIN (keep out cached for P2), P2 stores NT (final).
//
// P1 tiling: block B (=element bits 4..12) holds {bits 0..3} x {bits 13..21}
//   = 8192 elems = 2048 f4 in 32KB LDS; lf = hi*4+q, G=(hi<<11)|(B<<2)|q.
//   diag = Smid(B) + T1[hi] + T2[low4] + sum_{j in low4} C4[hi][j], built per block.
// P2 tiling: contiguous 2048-f4 tile (bits 0..12); bits 2..10 LDS partners,
//   bits 11,12 = vreg[c^1], vreg[c^2] (register partners), bits 0,1 permutes.

#define THREADS 512
#define NBLK 512

typedef float fvec4 __attribute__((ext_vector_type(4)));

__device__ __forceinline__ int uidx(int i, int j) {
    // np.triu_indices(22, k=1) row-major flatten, i<j
    return i * (43 - i) / 2 + (j - i - 1);
}

// ---------------- Pass 1: diag + hi butterfly (element bits 13..21) ----------------
__global__ __launch_bounds__(THREADS, 4) void ryd_hi_kernel(
        const float* __restrict__ state, const float* __restrict__ rabi,
        const float* __restrict__ detune, const float* __restrict__ U,
        float* __restrict__ out) {
    __shared__ float4 tileS[2048];               // 32 KB: lf = hi*4 + q
    __shared__ float T1s[512];                   // D(hi) + X(mid,hi)
    __shared__ __align__(16) float C4s[512][4];  // X(low4 bit j, hi)
    __shared__ __align__(16) float T2s[16];      // D(low4) + X(low4,mid)
    __shared__ float Us[231];
    __shared__ float dets[22];

    const float4* __restrict__ sF4 = (const float4*)state;
    float4* __restrict__ oF4 = (float4*)out;
    const unsigned t = threadIdx.x;
    const unsigned B = blockIdx.x;               // element bits 4..12 (qubit 17-i for bit i)
    const unsigned q = t & 3u;                   // f4 bits 0..1 (element bits 2..3), chunk-invariant

    if (t < 231u) Us[t] = U[t];
    else if (t < 253u) dets[t - 231u] = detune[t - 231u];

    // own loads first (latency hides under table build)
    float4 vreg[4];
    unsigned Gidx[4];
#pragma unroll
    for (int c = 0; c < 4; ++c) {
        const unsigned lf = t + 512u * (unsigned)c;
        const unsigned hi = lf >> 2;             // element bits 13..21 (qubit 8-j for bit j)
        const unsigned G = (hi << 11) | (B << 2) | q;
        Gidx[c] = G;
        vreg[c] = sF4[G];
    }
    __syncthreads();    // Us/dets visible

    // T1s[t] and C4s[t][*]: one hi value per thread
    {
        const unsigned h = t;
        float d = 0.f;
#pragma unroll
        for (int j = 0; j < 9; ++j) {
            if ((h >> j) & 1u) {
                d -= dets[8 - j];
#pragma unroll
                for (int j1 = 0; j1 < j; ++j1)
                    if ((h >> j1) & 1u) d += Us[uidx(8 - j, 8 - j1)];   // qubit(8-j) < qubit(8-j1)
#pragma unroll
                for (int i = 0; i < 9; ++i)
                    if ((B >> i) & 1u) d += Us[uidx(8 - j, 17 - i)];    // hi qubit < mid qubit
            }
        }
        T1s[t] = d;
#pragma unroll
        for (int j = 0; j < 4; ++j) {            // low4 bit j <-> qubit 21-j
            float cc = 0.f;
#pragma unroll
            for (int jh = 0; jh < 9; ++jh)
                if ((h >> jh) & 1u) cc += Us[uidx(8 - jh, 21 - j)];
            C4s[t][j] = cc;
        }
    }
    if (t < 16u) {
        const unsigned m4 = t;
        float s = 0.f;
        for (int j = 0; j < 4; ++j) {
            if ((m4 >> j) & 1u) {
                s -= dets[21 - j];
                for (int j1 = 0; j1 < j; ++j1)
                    if ((m4 >> j1) & 1u) s += Us[uidx(21 - j, 21 - j1)];
                for (int i = 0; i < 9; ++i)
                    if ((B >> i) & 1u) s += Us[uidx(17 - i, 21 - j)];   // mid qubit < low4 qubit
            }
        }
        T2s[t] = s;
    }
    // Smid: diag within block-constant mid bits (computed redundantly per thread)
    float Smid = 0.f;
#pragma unroll
    for (int i2 = 0; i2 < 9; ++i2) {
        if ((B >> i2) & 1u) {
            Smid -= dets[17 - i2];
#pragma unroll
            for (int i1 = 0; i1 < i2; ++i1)
                if ((B >> i1) & 1u) Smid += Us[uidx(17 - i2, 17 - i1)];
        }
    }
    // commit tile
#pragma unroll
    for (int c = 0; c < 4; ++c)
        tileS[t + 512u * (unsigned)c] = vreg[c];
    __syncthreads();

    float cb[9];
#pragma unroll
    for (int j = 0; j < 9; ++j) cb[j] = 0.5f * rabi[8 - j];   // element bit 13+j <-> qubit 8-j
    const float4 t2 = ((const float4*)T2s)[q];                // T2[(q<<2)|m] in comps

#pragma unroll
    for (int c = 0; c < 4; ++c) {
        const unsigned lf = t + 512u * (unsigned)c;
        const unsigned hi = lf >> 2;
        const float4 v = vreg[c];
        const float T1h = T1s[hi];
        const float4 c4 = *(const float4*)C4s[hi];
        const float base = Smid + T1h + ((q & 1u) ? c4.z : 0.f) + ((q & 2u) ? c4.w : 0.f);
        const float d0 = base + t2.x;
        const float d1 = base + c4.x + t2.y;
        const float d2 = base + c4.y + t2.z;
        const float d3 = base + c4.x + c4.y + t2.w;
        float4 acc;
        acc.x = d0 * v.x; acc.y = d1 * v.y; acc.z = d2 * v.z; acc.w = d3 * v.w;
#pragma unroll
        for (int j = 0; j < 9; ++j) {            // hi-bit flips: LDS-local
            const float4 p = tileS[lf ^ (4u << j)];
            acc.x += cb[j] * p.x; acc.y += cb[j] * p.y;
            acc.z += cb[j] * p.z; acc.w += cb[j] * p.w;
        }
        oF4[Gidx[c]] = acc;    // PLAIN store: stays cached for pass 2
    }
}

// ---------------- Pass 2: lo butterfly (element bits 0..12), accumulates ----------------
__global__ __launch_bounds__(THREADS, 4) void ryd_lo_kernel(
        const float* __restrict__ state, const float* __restrict__ rabi,
        float* __restrict__ out) {
    __shared__ float4 tileS[2048];               // 32 KB contiguous tile
    const float4* __restrict__ sF4 = (const float4*)state;
    float4* __restrict__ oF4 = (float4*)out;
    const unsigned t = threadIdx.x;
    const unsigned tbase = blockIdx.x * 2048u;

    float4 vreg[4], prev[4];
#pragma unroll
    for (int c = 0; c < 4; ++c) {
        vreg[c] = sF4[tbase + t + 512u * (unsigned)c];
        prev[c] = oF4[tbase + t + 512u * (unsigned)c];   // pass-1 partial (L2/L3 hit)
    }
#pragma unroll
    for (int c = 0; c < 4; ++c)
        tileS[t + 512u * (unsigned)c] = vreg[c];
    __syncthreads();

    const float r0  = 0.5f * rabi[21];   // element bit 0
    const float r1  = 0.5f * rabi[20];   // element bit 1
    const float r11 = 0.5f * rabi[10];   // element bit 11 (= vreg[c^1])
    const float r12 = 0.5f * rabi[9];    // element bit 12 (= vreg[c^2])
    float rb[9];
#pragma unroll
    for (int j = 0; j < 9; ++j) rb[j] = 0.5f * rabi[19 - j];  // element bit 2+j <-> qubit 19-j

#pragma unroll
    for (int c = 0; c < 4; ++c) {
        const unsigned f = t + 512u * (unsigned)c;
        const float4 v = vreg[c];
        float4 acc = prev[c];
        // bit 0: swap within float pairs
        acc.x += r0 * v.y; acc.y += r0 * v.x; acc.z += r0 * v.w; acc.w += r0 * v.z;
        // bit 1: swap halves of the float4
        acc.x += r1 * v.z; acc.y += r1 * v.w; acc.z += r1 * v.x; acc.w += r1 * v.y;
        // bits 11,12: this thread's other chunks (registers)
        {
            const float4 pa = vreg[c ^ 1];
            const float4 pb = vreg[c ^ 2];
            acc.x += r11 * pa.x; acc.y += r11 * pa.y; acc.z += r11 * pa.z; acc.w += r11 * pa.w;
            acc.x += r12 * pb.x; acc.y += r12 * pb.y; acc.z += r12 * pb.z; acc.w += r12 * pb.w;
        }
        // bits 2..10: LDS partners
#pragma unroll
        for (int j = 0; j < 9; ++j) {
            const float4 p = tileS[f ^ (1u << j)];
            acc.x += rb[j] * p.x; acc.y += rb[j] * p.y;
            acc.z += rb[j] * p.z; acc.w += rb[j] * p.w;
        }
        // final output: NT store
        union { float4 s4; fvec4 v4; } u;
        u.s4 = acc;
        __builtin_nontemporal_store(
            u.v4, reinterpret_cast<fvec4*>(oF4 + tbase + f));
    }
}

extern "C" void kernel_launch(void* const* d_in, const int* in_sizes, int n_in,
                              void* d_out, int out_size, void* d_ws, size_t ws_size,
                              hipStream_t stream) {
    const float* state  = (const float*)d_in[0];
    const float* rabi   = (const float*)d_in[1];
    const float* detune = (const float*)d_in[2];
    const float* U      = (const float*)d_in[3];
    float* out = (float*)d_out;
    (void)in_sizes; (void)n_in; (void)out_size; (void)d_ws; (void)ws_size;

    hipLaunchKernelGGL(ryd_hi_kernel, dim3(NBLK), dim3(THREADS), 0, stream,
                       state, rabi, detune, U, out);
    hipLaunchKernelGGL(ryd_lo_kernel, dim3(NBLK), dim3(THREADS), 0, stream,
                       state, rabi, out);
}

// Round 13
// 24.642 us; speedup vs baseline: 1.0272x; 1.0272x over previous
//
#include <hip/hip_runtime.h>

// Rydberg Hamiltonian apply: out[k] = diag(k)*state[k] + sum_b c_b * state[k ^ (1<<b)]
// N_QUBITS=22, DIM=2^22. Element bit b <-> qubit (21-b). c_b = 0.5*rabi[21-b].
//
// OCCUPANCY round: 1024 blocks x 512 threads (4 blocks/CU available), half tiles.
//  - block owns 1024 f4 = element bits 0..11 (16 KB LDS tile)
//  - bits 0..1: register permutes; bit 11: vreg[c^1] (chunk partner in regs)
//  - bits 2..10: LDS partners (masks 1..256, closed within the 1024-f4 tile)
//  - bits 12..18 (j=0..6): same-XCD L2 partners (128-half swizzle group = 2 MB)
//  - bits 19..21 (j=7..9): L3 partners, ping-pong prefetched one chunk ahead,
//    consumed OLDEST-FIRST (in-order vmcnt retire)
//  - register diet so occupancy can rise: dlo in 4 regs (R7-verified math),
//    all rabi coeffs + cj cross terms in SGPRs via readfirstlane
//  - NT stores (write-once)

#define THREADS 512
#define NBLK 1024

typedef float fvec4 __attribute__((ext_vector_type(4)));

__device__ __forceinline__ int uidx(int i, int j) {
    // np.triu_indices(22, k=1) row-major flatten, i<j
    return i * (43 - i) / 2 + (j - i - 1);
}

__device__ __forceinline__ float to_sgpr(float x) {
    return __uint_as_float(__builtin_amdgcn_readfirstlane(__float_as_uint(x)));
}

__global__ __launch_bounds__(THREADS, 4) void ryd_kernel(
        const float* __restrict__ state, const float* __restrict__ rabi,
        const float* __restrict__ detune, const float* __restrict__ U,
        float* __restrict__ out) {
    __shared__ float4 tileS[1024];   // 16 KB: element bits 0..11
    __shared__ float Us[231];
    __shared__ float dets[22];
    __shared__ float CJ[2][11];
    __shared__ float S2v[2];

    const float4* __restrict__ sF4 = (const float4*)state;
    float4* __restrict__ oF4 = (float4*)out;
    const unsigned t = threadIdx.x;
    const unsigned blk = blockIdx.x;
    // XCD swizzle: each XCD's 128 co-resident blocks own a contiguous
    // 128-half group (2 MB <= 4 MB L2); partner halves hf^2^j, j<7 in-group.
    const unsigned hf = ((blk & 7u) << 7) | (blk >> 3);   // [0,1024)
    const unsigned tbase = hf * 1024u;                    // f4 base

    // ---- stage U, detune into LDS ----
    if (t < 231u) Us[t] = U[t];
    else if (t < 253u) dets[t - 231u] = detune[t - 231u];

    // ---- issue own tile + chunk-0's L3 partners before table math ----
    float4 vreg[2];
    vreg[0] = sF4[tbase + t];
    vreg[1] = sF4[tbase + t + 512u];
    float4 pgl[2][3];   // pgl[c] = chunk c's L3 partners (element bits 19..21)
#pragma unroll
    for (int j = 0; j < 3; ++j)
        pgl[0][j] = sF4[(tbase + t) ^ (1024u << (7 + j))];

    __syncthreads();    // Us/dets visible

    // ---- register dlo over m11 = 4t+comp (element bits 0..10), chunk-invariant ----
    float dlx, dly, dlz, dlw;
    {
        float B = 0.f, R0 = 0.f, R1 = 0.f;
#pragma unroll
        for (int j2 = 0; j2 < 9; ++j2) {
            const int q2 = 19 - j2;            // m11 bit j2+2 <-> qubit 19-j2
            float ap = -dets[q2];
#pragma unroll
            for (int j1 = 0; j1 < j2; ++j1)
                ap += ((t >> j1) & 1u) ? Us[uidx(q2, 19 - j1)] : 0.f;
            const bool b2 = (t >> j2) & 1u;
            B  += b2 ? ap : 0.f;
            R0 += b2 ? Us[uidx(q2, 21)] : 0.f;  // pair with qubit 21 (m11 bit 0)
            R1 += b2 ? Us[uidx(q2, 20)] : 0.f;  // pair with qubit 20 (m11 bit 1)
        }
        const float w0 = -dets[21] + R0;
        const float w1 = -dets[20] + R1;
        dlx = B; dly = B + w0; dlz = B + w1;
        dlw = B + w0 + w1 + Us[uidx(20, 21)];
    }
    // ---- per-block hi tables: hi11 = (hf<<1)|c (element bits 11..21) ----
    if (t < 22u) {
        const int c = (int)t / 11, j = (int)t % 11;
        const unsigned h = (hf << 1) | (unsigned)c;     // bit jh <-> qubit 10-jh
        float cc = 0.f;
        for (int jh = 0; jh < 11; ++jh)
            if ((h >> jh) & 1u) cc += Us[uidx(10 - jh, 21 - j)];
        CJ[c][j] = cc;
    } else if (t < 24u) {
        const int c = (int)t - 22;
        const unsigned h = (hf << 1) | (unsigned)c;
        float s = 0.f;
        for (int j2 = 0; j2 < 11; ++j2) {
            if ((h >> j2) & 1u) {
                s -= dets[10 - j2];
                for (int j1 = 0; j1 < j2; ++j1)
                    if ((h >> j1) & 1u) s += Us[uidx(10 - j2, 10 - j1)];
            }
        }
        S2v[c] = s;
    }

    // ---- commit own tile ----
    tileS[t] = vreg[0];
    tileS[t + 512u] = vreg[1];
    __syncthreads();   // tables + tile ready

    // ---- coefficients in SGPRs ----
    const float r0   = to_sgpr(0.5f * rabi[21]);   // element bit 0
    const float r1   = to_sgpr(0.5f * rabi[20]);   // element bit 1
    const float rb11 = to_sgpr(0.5f * rabi[10]);   // element bit 11 (= vreg[c^1])
    float rls[9];
#pragma unroll
    for (int j = 0; j < 9; ++j) rls[j] = to_sgpr(0.5f * rabi[19 - j]);  // bit 2+j
    float cbs[10];
#pragma unroll
    for (int j = 0; j < 10; ++j) cbs[j] = to_sgpr(0.5f * rabi[9 - j]);  // bit 12+j

#pragma unroll
    for (int c = 0; c < 2; ++c) {
        const unsigned f = t + 512u * (unsigned)c;   // [0,1024)
        const unsigned F = tbase + f;
        // in-XCD L2 partners (element bits 12..18)
        float4 pg[7];
#pragma unroll
        for (int j = 0; j < 7; ++j)
            pg[j] = sF4[F ^ (1024u << j)];
        // prefetch chunk-1's L3 partners (full chunk of lead)
        if (c == 0) {
#pragma unroll
            for (int j = 0; j < 3; ++j)
                pgl[1][j] = sF4[(F + 512u) ^ (1024u << (7 + j))];
        }

        float cj[11];
#pragma unroll
        for (int j = 0; j < 11; ++j) cj[j] = to_sgpr(CJ[c][j]);
        float s = to_sgpr(S2v[c]);
#pragma unroll
        for (int j = 0; j < 9; ++j)
            s += ((t >> j) & 1u) ? cj[j + 2] : 0.f;   // element bits 2..10 = t bits
        const float4 v = vreg[c];
        const float d0 = s + dlx;
        const float d1 = s + cj[0] + dly;
        const float d2 = s + cj[1] + dlz;
        const float d3 = s + cj[0] + cj[1] + dlw;
        float4 acc;
        acc.x = d0 * v.x; acc.y = d1 * v.y; acc.z = d2 * v.z; acc.w = d3 * v.w;
        // element bit 0: swap within float pairs
        acc.x += r0 * v.y; acc.y += r0 * v.x; acc.z += r0 * v.w; acc.w += r0 * v.z;
        // element bit 1: swap halves of the float4
        acc.x += r1 * v.z; acc.y += r1 * v.w; acc.z += r1 * v.x; acc.w += r1 * v.y;
        // element bit 11: this thread's other chunk (register)
        {
            const float4 p = vreg[c ^ 1];
            acc.x += rb11 * p.x; acc.y += rb11 * p.y;
            acc.z += rb11 * p.z; acc.w += rb11 * p.w;
        }
        // element bits 2..10: LDS partners (covers pg latency)
#pragma unroll
        for (int j = 0; j < 9; ++j) {
            const float4 p = tileS[f ^ (1u << j)];
            acc.x += rls[j] * p.x; acc.y += rls[j] * p.y;
            acc.z += rls[j] * p.z; acc.w += rls[j] * p.w;
        }
        // element bits 19..21: consume OLDEST outstanding first (in-order retire)
#pragma unroll
        for (int j = 0; j < 3; ++j) {
            const float4 p = pgl[c][j];
            acc.x += cbs[7 + j] * p.x; acc.y += cbs[7 + j] * p.y;
            acc.z += cbs[7 + j] * p.z; acc.w += cbs[7 + j] * p.w;
        }
        // element bits 12..18: in-chunk L2 partners
#pragma unroll
        for (int j = 0; j < 7; ++j) {
            const float4 p = pg[j];
            acc.x += cbs[j] * p.x; acc.y += cbs[j] * p.y;
            acc.z += cbs[j] * p.z; acc.w += cbs[j] * p.w;
        }
        // write-once output: non-temporal
        union { float4 s4; fvec4 v4; } u;
        u.s4 = acc;
        __builtin_nontemporal_store(u.v4, reinterpret_cast<fvec4*>(oF4 + F));
    }
}

extern "C" void kernel_launch(void* const* d_in, const int* in_sizes, int n_in,
                              void* d_out, int out_size, void* d_ws, size_t ws_size,
                              hipStream_t stream) {
    const float* state  = (const float*)d_in[0];
    const float* rabi   = (const float*)d_in[1];
    const float* detune = (const float*)d_in[2];
    const float* U      = (const float*)d_in[3];
    float* out = (float*)d_out;
    (void)in_sizes; (void)n_in; (void)out_size; (void)d_ws; (void)ws_size;

    hipLaunchKernelGGL(ryd_kernel, dim3(NBLK), dim3(THREADS), 0, stream,
                       state, rabi, detune, U, out);
}